// Round 3
// baseline (63.119 us; speedup 1.0000x reference)
//
#include <hip/hip_runtime.h>

#define S_LEN 64000
#define B_N   64
#define CH    16          // steps per chunk (serial chain per wave)
#define NCH   4000        // S_LEN / CH
#define KPL   8           // chunks per thread in scan kernel
#define SCAN_T 512        // scan threads: SCAN_T*KPL = 4096 >= NCH

struct Aff { float m00, m01, m10, m11, v0, v1; };

__device__ __forceinline__ Aff aff_id() {
    Aff r; r.m00 = 1.f; r.m01 = 0.f; r.m10 = 0.f; r.m11 = 1.f; r.v0 = 0.f; r.v1 = 0.f;
    return r;
}

// X ∘ Y : apply Y first, then X
__device__ __forceinline__ Aff aff_comp(const Aff& X, const Aff& Y) {
    Aff r;
    r.m00 = fmaf(X.m00, Y.m00, X.m01 * Y.m10);
    r.m01 = fmaf(X.m00, Y.m01, X.m01 * Y.m11);
    r.m10 = fmaf(X.m10, Y.m00, X.m11 * Y.m10);
    r.m11 = fmaf(X.m10, Y.m01, X.m11 * Y.m11);
    r.v0  = fmaf(X.m00, Y.v0, fmaf(X.m01, Y.v1, X.v0));
    r.v1  = fmaf(X.m10, Y.v0, fmaf(X.m11, Y.v1, X.v1));
    return r;
}

// Per-step transform: state' = A*state + c, A = 2H - I, c = 2*gHBx
__device__ __forceinline__ Aff svf_step(float g, float R, float x) {
    Aff a;
    float T  = 1.0f / fmaf(g, g + R, 1.0f);
    float gT = g * T;
    a.m00 = fmaf(2.0f, T, -1.0f);
    a.m01 = -2.0f * gT;
    a.m10 =  2.0f * gT;
    a.m11 = fmaf(2.0f, fmaf(R, gT, T), -1.0f);
    a.v0  = a.m10 * x;
    a.v1  = g * a.v0;
    return a;
}

// Pass 1: 4 waves/block, wave w composes chunk p = bid*4+w (16 steps).
// Two independent half-chunk accumulators (ILP-2 on the FMA chain); full
// unroll so all 48 loads issue early. Lane = batch -> 256 B coalesced.
__global__ __launch_bounds__(256) void k_chunk(
    const float* __restrict__ audio, const float* __restrict__ g,
    const float* __restrict__ twoR, float* __restrict__ wsM)
{
    const int b = threadIdx.x & 63;
    const int w = threadIdx.x >> 6;
    const int p = blockIdx.x * 4 + w;
    const int base = p * CH * B_N + b;

    Aff lo = aff_id(), hi = aff_id();
#pragma unroll
    for (int i = 0; i < CH / 2; ++i) {
        const int i0 = base + i * B_N;
        const int i1 = base + (i + CH / 2) * B_N;
        Aff a0 = svf_step(g[i0], twoR[i0], audio[i0]);
        Aff a1 = svf_step(g[i1], twoR[i1], audio[i1]);
        lo = aff_comp(a0, lo);
        hi = aff_comp(a1, hi);
    }
    Aff acc = aff_comp(hi, lo);

    const int o = p * B_N + b;
    const int stride = NCH * B_N;
    wsM[o]              = acc.m00;
    wsM[o + 1 * stride] = acc.m01;
    wsM[o + 2 * stride] = acc.m10;
    wsM[o + 3 * stride] = acc.m11;
    wsM[o + 4 * stride] = acc.v0;
    wsM[o + 5 * stride] = acc.v1;
}

// Pass 2: one block (512 threads) per batch. Thread t owns chunks
// [t*KPL, t*KPL+KPL). Thread-local compose -> wave shuffle scan -> LDS
// cross-wave combine -> emit per-chunk entry states (float2).
__global__ __launch_bounds__(SCAN_T) void k_scan(
    const float* __restrict__ wsM, float2* __restrict__ sIn)
{
    const int b = blockIdx.x;
    const int t = threadIdx.x;
    const int lane = t & 63;
    const int wave = t >> 6;
    const int stride = NCH * B_N;

    Aff cM[KPL];
#pragma unroll
    for (int k = 0; k < KPL; ++k) {
        const int p = t * KPL + k;
        if (p < NCH) {
            const int o = p * B_N + b;
            cM[k].m00 = wsM[o];
            cM[k].m01 = wsM[o + 1 * stride];
            cM[k].m10 = wsM[o + 2 * stride];
            cM[k].m11 = wsM[o + 3 * stride];
            cM[k].v0  = wsM[o + 4 * stride];
            cM[k].v1  = wsM[o + 5 * stride];
        } else {
            cM[k] = aff_id();
        }
    }

    // thread-local inclusive compose (increasing chunk order)
    Aff acc = aff_id();
#pragma unroll
    for (int k = 0; k < KPL; ++k) acc = aff_comp(cM[k], acc);

    // wave-inclusive Hillis-Steele scan
#pragma unroll
    for (int d = 1; d < 64; d <<= 1) {
        Aff o;
        o.m00 = __shfl_up(acc.m00, (unsigned)d, 64);
        o.m01 = __shfl_up(acc.m01, (unsigned)d, 64);
        o.m10 = __shfl_up(acc.m10, (unsigned)d, 64);
        o.m11 = __shfl_up(acc.m11, (unsigned)d, 64);
        o.v0  = __shfl_up(acc.v0,  (unsigned)d, 64);
        o.v1  = __shfl_up(acc.v1,  (unsigned)d, 64);
        if (lane >= d) acc = aff_comp(acc, o);
    }

    // wave totals -> LDS
    __shared__ Aff wt[SCAN_T / 64];
    if (lane == 63) wt[wave] = acc;
    __syncthreads();

    // exclusive within wave
    Aff E;
    E.m00 = __shfl_up(acc.m00, 1u, 64);
    E.m01 = __shfl_up(acc.m01, 1u, 64);
    E.m10 = __shfl_up(acc.m10, 1u, 64);
    E.m11 = __shfl_up(acc.m11, 1u, 64);
    E.v0  = __shfl_up(acc.v0,  1u, 64);
    E.v1  = __shfl_up(acc.v1,  1u, 64);
    if (lane == 0) E = aff_id();

    // compose earlier waves' totals (chunk order: wave 0 first)
    Aff P = aff_id();
    for (int j = 0; j < wave; ++j) P = aff_comp(wt[j], P);
    E = aff_comp(E, P);

    // entry state of chunk t*KPL: apply E to s0 = (1,1)
    float s0 = E.m00 + E.m01 + E.v0;
    float s1 = E.m10 + E.m11 + E.v1;

#pragma unroll
    for (int k = 0; k < KPL; ++k) {
        const int p = t * KPL + k;
        if (p < NCH) {
            sIn[p * B_N + b] = make_float2(s0, s1);
            float n0 = fmaf(cM[k].m00, s0, fmaf(cM[k].m01, s1, cM[k].v0));
            float n1 = fmaf(cM[k].m10, s0, fmaf(cM[k].m11, s1, cM[k].v1));
            s0 = n0; s1 = n1;
        }
    }
}

// Pass 3: 4 waves/block, wave w replays chunk p = bid*4+w from its entry
// state; block covers 64 consecutive steps; transpose via padded LDS so
// [B,S] stores are 256 B coalesced.
__global__ __launch_bounds__(256) void k_out(
    const float* __restrict__ audio, const float* __restrict__ g,
    const float* __restrict__ twoR, const float* __restrict__ mix,
    const float2* __restrict__ sIn, float* __restrict__ out)
{
    __shared__ float tile[64 * 65];
    const int b = threadIdx.x & 63;
    const int w = threadIdx.x >> 6;
    const int p = blockIdx.x * 4 + w;
    const int tbase = p * CH;

    float2 s = sIn[p * B_N + b];
    float s0 = s.x, s1 = s.y;

#pragma unroll
    for (int i = 0; i < CH; ++i) {
        const int idx = (tbase + i) * B_N + b;
        float gg = g[idx], R = twoR[idx], x = audio[idx];
        float m0 = mix[idx * 3], m1 = mix[idx * 3 + 1], m2 = mix[idx * 3 + 2];

        float T  = 1.0f / fmaf(gg, gg + R, 1.0f);
        float gT = gg * T;
        float b0 = gT * x;
        float b1 = gg * b0;
        float Y0 = fmaf(T, s0, fmaf(-gT, s1, b0));
        float Y1 = fmaf(gT, s0, fmaf(fmaf(R, gT, T), s1, b1));
        s0 = fmaf(2.0f, Y0, -s0);
        s1 = fmaf(2.0f, Y1, -s1);

        float yh = x - fmaf(R, Y0, Y1);
        float y  = fmaf(R * m0, Y0, fmaf(m1, Y1, m2 * yh));

        tile[(w * CH + i) * 65 + b] = y;
    }
    __syncthreads();

    // block writes out[r][colbase .. colbase+63]; each wave stores 256 B
    // contiguous rows; LDS reads stride-65 -> 2-way conflict max (free).
    const int col = threadIdx.x & 63;
    const int r0  = threadIdx.x >> 6;
    const int colbase = blockIdx.x * 64;
#pragma unroll
    for (int r = r0; r < 64; r += 4) {
        out[r * S_LEN + colbase + col] = tile[col * 65 + r];
    }
}

extern "C" void kernel_launch(void* const* d_in, const int* in_sizes, int n_in,
                              void* d_out, int out_size, void* d_ws, size_t ws_size,
                              hipStream_t stream)
{
    const float* audio = (const float*)d_in[0];
    const float* g     = (const float*)d_in[1];
    const float* twoR  = (const float*)d_in[2];
    const float* mix   = (const float*)d_in[3];
    float* out = (float*)d_out;

    float* wsM = (float*)d_ws;                    // 6 * NCH * 64 floats (~6.1 MB)
    float2* sIn = (float2*)(wsM + 6 * NCH * B_N); // NCH * 64 float2 (~2.0 MB)

    k_chunk<<<dim3(NCH / 4), dim3(256), 0, stream>>>(audio, g, twoR, wsM);
    k_scan <<<dim3(B_N), dim3(SCAN_T), 0, stream>>>(wsM, sIn);
    k_out  <<<dim3(NCH / 4), dim3(256), 0, stream>>>(audio, g, twoR, mix, sIn, out);
}

// Round 4
// 37.733 us; speedup vs baseline: 1.6728x; 1.6728x over previous
//
#include <hip/hip_runtime.h>

#define S_LEN  64000
#define B_N    64
#define MCH    8            // steps per micro-chunk (one wave's serial chain)
#define WPB    8            // waves per block (micros per macro)
#define BSTEPS (MCH * WPB)  // 64 steps per block / macro
#define NBLK   (S_LEN / BSTEPS) // 1000 macro chunks
#define KPL    4            // macros per thread in scan
#define SCAN_T 256          // 256*4 = 1024 >= 1000

struct Aff { float m00, m01, m10, m11, v0, v1; };

__device__ __forceinline__ Aff aff_id() {
    Aff r; r.m00 = 1.f; r.m01 = 0.f; r.m10 = 0.f; r.m11 = 1.f; r.v0 = 0.f; r.v1 = 0.f;
    return r;
}

// X ∘ Y : apply Y first, then X
__device__ __forceinline__ Aff aff_comp(const Aff& X, const Aff& Y) {
    Aff r;
    r.m00 = fmaf(X.m00, Y.m00, X.m01 * Y.m10);
    r.m01 = fmaf(X.m00, Y.m01, X.m01 * Y.m11);
    r.m10 = fmaf(X.m10, Y.m00, X.m11 * Y.m10);
    r.m11 = fmaf(X.m10, Y.m01, X.m11 * Y.m11);
    r.v0  = fmaf(X.m00, Y.v0, fmaf(X.m01, Y.v1, X.v0));
    r.v1  = fmaf(X.m10, Y.v0, fmaf(X.m11, Y.v1, X.v1));
    return r;
}

// Per-step transform: state' = A*state + c, A = 2H - I, c = 2*gHBx
__device__ __forceinline__ Aff svf_step(float g, float R, float x) {
    Aff a;
    float T  = 1.0f / fmaf(g, g + R, 1.0f);
    float gT = g * T;
    a.m00 = fmaf(2.0f, T, -1.0f);
    a.m01 = -2.0f * gT;
    a.m10 =  2.0f * gT;
    a.m11 = fmaf(2.0f, fmaf(R, gT, T), -1.0f);
    a.v0  = a.m10 * x;
    a.v1  = g * a.v0;
    return a;
}

// LDS staging, stride 7 floats per (micro, batch) -> 2-way banks max (free)
__device__ __forceinline__ void aff_store_lds(float* p, const Aff& a) {
    p[0] = a.m00; p[1] = a.m01; p[2] = a.m10; p[3] = a.m11; p[4] = a.v0; p[5] = a.v1;
}
__device__ __forceinline__ Aff aff_load_lds(const float* p) {
    Aff a; a.m00 = p[0]; a.m01 = p[1]; a.m10 = p[2]; a.m11 = p[3]; a.v0 = p[4]; a.v1 = p[5];
    return a;
}
// Packed global Aff: 3 x float2 at element (p*64+b)*3 (8-B aligned)
__device__ __forceinline__ void aff_store_g(float2* p, const Aff& a) {
    p[0] = make_float2(a.m00, a.m01);
    p[1] = make_float2(a.m10, a.m11);
    p[2] = make_float2(a.v0,  a.v1);
}
__device__ __forceinline__ Aff aff_load_g(const float2* p) {
    float2 x = p[0], y = p[1], z = p[2];
    Aff a; a.m00 = x.x; a.m01 = x.y; a.m10 = y.x; a.m11 = y.y; a.v0 = z.x; a.v1 = z.y;
    return a;
}

// Pass 1: wave w composes 8-step micro transform; block composes its 8
// micros (64 steps) into one macro transform via LDS. Lane = batch.
__global__ __launch_bounds__(512) void k_macro(
    const float* __restrict__ audio, const float* __restrict__ g,
    const float* __restrict__ twoR, float2* __restrict__ wsMac)
{
    __shared__ float affs[WPB * B_N * 7];
    const int b   = threadIdx.x & 63;
    const int w   = threadIdx.x >> 6;
    const int blk = blockIdx.x;
    const int base = (blk * BSTEPS + w * MCH) * B_N + b;

    Aff acc = aff_id();
#pragma unroll
    for (int i = 0; i < MCH; ++i) {
        const int idx = base + i * B_N;
        acc = aff_comp(svf_step(g[idx], twoR[idx], audio[idx]), acc);
    }
    aff_store_lds(&affs[(w * B_N + b) * 7], acc);
    __syncthreads();

    if (w == 0) {
        Aff M = acc;  // micro 0 (this wave's own)
#pragma unroll
        for (int j = 1; j < WPB; ++j) {
            Aff A = aff_load_lds(&affs[(j * B_N + b) * 7]);
            M = aff_comp(A, M);
        }
        aff_store_g(&wsMac[(blk * B_N + b) * 3], M);
    }
}

// Pass 2: one block per batch scans the 1000 macro transforms and writes
// each macro's entry state (float2).
__global__ __launch_bounds__(SCAN_T) void k_scan(
    const float2* __restrict__ wsMac, float2* __restrict__ sIn)
{
    const int b    = blockIdx.x;
    const int t    = threadIdx.x;
    const int lane = t & 63;
    const int wave = t >> 6;

    Aff cM[KPL];
#pragma unroll
    for (int k = 0; k < KPL; ++k) {
        const int p = t * KPL + k;
        cM[k] = (p < NBLK) ? aff_load_g(&wsMac[(p * B_N + b) * 3]) : aff_id();
    }

    // thread-local inclusive compose (increasing macro order)
    Aff acc = aff_id();
#pragma unroll
    for (int k = 0; k < KPL; ++k) acc = aff_comp(cM[k], acc);

    // wave-inclusive Hillis-Steele scan
#pragma unroll
    for (int d = 1; d < 64; d <<= 1) {
        Aff o;
        o.m00 = __shfl_up(acc.m00, (unsigned)d, 64);
        o.m01 = __shfl_up(acc.m01, (unsigned)d, 64);
        o.m10 = __shfl_up(acc.m10, (unsigned)d, 64);
        o.m11 = __shfl_up(acc.m11, (unsigned)d, 64);
        o.v0  = __shfl_up(acc.v0,  (unsigned)d, 64);
        o.v1  = __shfl_up(acc.v1,  (unsigned)d, 64);
        if (lane >= d) acc = aff_comp(acc, o);
    }

    __shared__ Aff wt[SCAN_T / 64];
    if (lane == 63) wt[wave] = acc;
    __syncthreads();

    // exclusive within wave
    Aff E;
    E.m00 = __shfl_up(acc.m00, 1u, 64);
    E.m01 = __shfl_up(acc.m01, 1u, 64);
    E.m10 = __shfl_up(acc.m10, 1u, 64);
    E.m11 = __shfl_up(acc.m11, 1u, 64);
    E.v0  = __shfl_up(acc.v0,  1u, 64);
    E.v1  = __shfl_up(acc.v1,  1u, 64);
    if (lane == 0) E = aff_id();

    Aff P = aff_id();
    for (int j = 0; j < wave; ++j) P = aff_comp(wt[j], P);
    E = aff_comp(E, P);

    // entry state of macro t*KPL: apply E to s0 = (1,1)
    float s0 = E.m00 + E.m01 + E.v0;
    float s1 = E.m10 + E.m11 + E.v1;

#pragma unroll
    for (int k = 0; k < KPL; ++k) {
        const int p = t * KPL + k;
        if (p < NBLK) {
            sIn[p * B_N + b] = make_float2(s0, s1);
            float n0 = fmaf(cM[k].m00, s0, fmaf(cM[k].m01, s1, cM[k].v0));
            float n1 = fmaf(cM[k].m10, s0, fmaf(cM[k].m11, s1, cM[k].v1));
            s0 = n0; s1 = n1;
        }
    }
}

// Pass 3: wave w recomputes its micro transform, block shares micros via
// LDS, wave composes its within-block prefix -> exact entry state, then
// replays only 8 steps. Output transposed through padded LDS tile.
__global__ __launch_bounds__(512) void k_replay(
    const float* __restrict__ audio, const float* __restrict__ g,
    const float* __restrict__ twoR, const float* __restrict__ mix,
    const float2* __restrict__ sIn, float* __restrict__ out)
{
    __shared__ float lds[BSTEPS * 65];  // reused: first WPB*64*7 = Aff staging
    const int b   = threadIdx.x & 63;
    const int w   = threadIdx.x >> 6;
    const int blk = blockIdx.x;
    const int base = (blk * BSTEPS + w * MCH) * B_N + b;

    // load this wave's 8 steps of inputs (all independent -> deep in flight)
    float gv[MCH], Rv[MCH], xv[MCH], m0v[MCH], m1v[MCH], m2v[MCH];
#pragma unroll
    for (int i = 0; i < MCH; ++i) {
        const int idx = base + i * B_N;
        gv[i] = g[idx]; Rv[i] = twoR[idx]; xv[i] = audio[idx];
        m0v[i] = mix[idx * 3]; m1v[i] = mix[idx * 3 + 1]; m2v[i] = mix[idx * 3 + 2];
    }

    // micro transform for this wave
    Aff acc = aff_id();
#pragma unroll
    for (int i = 0; i < MCH; ++i)
        acc = aff_comp(svf_step(gv[i], Rv[i], xv[i]), acc);
    aff_store_lds(&lds[(w * B_N + b) * 7], acc);
    __syncthreads();

    // entry state: within-block exclusive prefix applied to macro entry
    float2 sm = sIn[blk * B_N + b];
    Aff P = aff_id();
    for (int j = 0; j < w; ++j) {
        Aff A = aff_load_lds(&lds[(j * B_N + b) * 7]);
        P = aff_comp(A, P);
    }
    float s0 = fmaf(P.m00, sm.x, fmaf(P.m01, sm.y, P.v0));
    float s1 = fmaf(P.m10, sm.x, fmaf(P.m11, sm.y, P.v1));
    __syncthreads();  // prefix reads done before tile overwrites staging

    // replay 8 steps, write y into transpose tile
#pragma unroll
    for (int i = 0; i < MCH; ++i) {
        float gg = gv[i], R = Rv[i], x = xv[i];
        float T  = 1.0f / fmaf(gg, gg + R, 1.0f);
        float gT = gg * T;
        float b0 = gT * x;
        float b1 = gg * b0;
        float Y0 = fmaf(T, s0, fmaf(-gT, s1, b0));
        float Y1 = fmaf(gT, s0, fmaf(fmaf(R, gT, T), s1, b1));
        s0 = fmaf(2.0f, Y0, -s0);
        s1 = fmaf(2.0f, Y1, -s1);

        float yh = x - fmaf(R, Y0, Y1);
        float y  = fmaf(R * m0v[i], Y0, fmaf(m1v[i], Y1, m2v[i] * yh));

        lds[(w * MCH + i) * 65 + b] = y;
    }
    __syncthreads();

    // out[r][blk*64 + col]: 64-lane contiguous 256 B stores; LDS reads
    // stride-65 -> 2-way max (free)
    const int col = threadIdx.x & 63;
    const int r0  = threadIdx.x >> 6;
    const int colbase = blk * BSTEPS;
#pragma unroll
    for (int r = r0; r < B_N; r += WPB) {
        out[r * S_LEN + colbase + col] = lds[col * 65 + r];
    }
}

extern "C" void kernel_launch(void* const* d_in, const int* in_sizes, int n_in,
                              void* d_out, int out_size, void* d_ws, size_t ws_size,
                              hipStream_t stream)
{
    const float* audio = (const float*)d_in[0];
    const float* g     = (const float*)d_in[1];
    const float* twoR  = (const float*)d_in[2];
    const float* mix   = (const float*)d_in[3];
    float* out = (float*)d_out;

    float2* wsMac = (float2*)d_ws;               // NBLK*64*3 float2 (~1.5 MB)
    float2* sIn   = wsMac + NBLK * B_N * 3;      // NBLK*64 float2 (~0.5 MB)

    k_macro <<<dim3(NBLK), dim3(512), 0, stream>>>(audio, g, twoR, wsMac);
    k_scan  <<<dim3(B_N), dim3(SCAN_T), 0, stream>>>(wsMac, sIn);
    k_replay<<<dim3(NBLK), dim3(512), 0, stream>>>(audio, g, twoR, mix, sIn, out);
}